// Round 20
// baseline (1241.878 us; speedup 1.0000x reference)
//
#include <hip/hip_runtime.h>
#include <math.h>

// fp32 attention layer via split-bf16 (hi/lo) 3-term MFMA emulation.
// Interleaved storage: [row][(col/32)*64 + col%32 + plane*32].
// r20: attn KV-tile doubled to 64 rows/iter (32 iters) -- per-iter fixed
// costs (barrier, stage-drain) halved; V^T records direct-from-global
// (L2-hot, prefetched at half start, hidden under QK^T) keeps LDS at
// 64 KB -> 2 blocks/CU. GEMM: r16 (128x192, 2 blk/CU, fused QKV pack).

typedef unsigned int u32;
typedef unsigned short u16;
typedef __attribute__((ext_vector_type(8))) short bf16x8;
typedef __attribute__((ext_vector_type(4))) float f32x4;
typedef __attribute__((ext_vector_type(16))) float f32x16;

#define MFMA(a, b, c) __builtin_amdgcn_mfma_f32_16x16x32_bf16((a), (b), (c), 0, 0, 0)
#define MFMA32(a, b, c) __builtin_amdgcn_mfma_f32_32x32x16_bf16((a), (b), (c), 0, 0, 0)

#define GLDS16(g, l) __builtin_amdgcn_global_load_lds( \
    (const __attribute__((address_space(1))) u32*)(g), \
    (__attribute__((address_space(3))) u32*)(l), 16, 0, 0)

__device__ __forceinline__ u16 f2bf(float f) {
  u32 u = __builtin_bit_cast(u32, f);
  return (u16)((u + 0x7fffu + ((u >> 16) & 1u)) >> 16);  // RNE
}
__device__ __forceinline__ float bf2f(u16 h) {
  u32 u = ((u32)h) << 16;
  return __builtin_bit_cast(float, u);
}
__device__ __forceinline__ void split2(float f, u16& h, u16& l) {
  h = f2bf(f);
  l = f2bf(f - bf2f(h));
}
__device__ __forceinline__ bf16x8 ld16(const u16* p) {
  return *reinterpret_cast<const bf16x8*>(p);
}

// ---------------------------------------------------------------- split ----
// fp32 [R][3072] -> interleaved hi/lo u16 [R][6144]. 8 floats/thread.
__global__ void split_kernel(const float* __restrict__ src, u16* __restrict__ dst,
                             long n) {
  long i = ((long)blockIdx.x * 256 + threadIdx.x) * 8;
  if (i >= n) return;
  const float4 v0 = *reinterpret_cast<const float4*>(src + i);
  const float4 v1 = *reinterpret_cast<const float4*>(src + i + 4);
  const u32 i32 = (u32)i;
  const u32 row = i32 / 3072u;
  const u32 col = i32 - row * 3072u;
  const long base = (long)row * 6144 + (col >> 5) * 64 + (col & 31);
  bf16x8 hv, lv;
  u16 h, l;
  split2(v0.x, h, l); hv[0] = (short)h; lv[0] = (short)l;
  split2(v0.y, h, l); hv[1] = (short)h; lv[1] = (short)l;
  split2(v0.z, h, l); hv[2] = (short)h; lv[2] = (short)l;
  split2(v0.w, h, l); hv[3] = (short)h; lv[3] = (short)l;
  split2(v1.x, h, l); hv[4] = (short)h; lv[4] = (short)l;
  split2(v1.y, h, l); hv[5] = (short)h; lv[5] = (short)l;
  split2(v1.z, h, l); hv[6] = (short)h; lv[6] = (short)l;
  split2(v1.w, h, l); hv[7] = (short)h; lv[7] = (short)l;
  *reinterpret_cast<bf16x8*>(dst + base) = hv;
  *reinterpret_cast<bf16x8*>(dst + base + 32) = lv;
}

// --------------------------------------- 128x192 3-term GEMM, 32x32x16 ----
// C = Ah*Bh^T + Ah*Bl^T + Al*Bh^T; A2[M][6144], B2[N][6144] interleaved.
// K=3072 -> NT=96 tiles of 32 (2 MFMA k-subs of 16). 4 waves (2M x 2N),
// wave tile 64x96, acc 6 x f32x16 = 96 VGPR. LDS 80 KiB -> 2 blocks/CU.
// MODE 1: fp32 C + bias (o_proj). MODE 2: QKV epilogue -- bn<16: compact
// Q2 [4096][6144]; bn 16..31: K packed records; bn>=32: V^T packed records
// (LDS-transpose via P[2][64][200], reusing staging LDS post-loop).
template <int MODE>
__global__ __launch_bounds__(256, 2) void gemm32(
    const u16* __restrict__ A2, const u16* __restrict__ B2,
    int M, int N, u16* __restrict__ C2, u16* __restrict__ Kp,
    u16* __restrict__ Vp, float* __restrict__ Cf, const float* __restrict__ bias) {
  constexpr int NT = 96;
  __shared__ u16 shm[2 * 128 * 64 + 2 * 192 * 64];  // 80 KiB
  u16* const uA = shm;                  // 2 x 128x64
  u16* const uB = shm + 2 * 128 * 64;   // 2 x 192x64
  const int tid = threadIdx.x;
  const int lane = tid & 63;
  const int w = tid >> 6;             // 0..3
  const int wm = w >> 1, wn = w & 1;  // 2M x 2N
  const int l31 = lane & 31;
  const int l5 = lane >> 5;

  const int mt = M >> 7;  // 128-row tiles
  const int nwg = gridDim.x;
  const int bid = blockIdx.x;
  const int wg = (bid & 7) * (nwg >> 3) + (bid >> 3);  // XCD swizzle (nwg%8==0)
  const int bm = wg % mt, bn = wg / mt;

  const int srow = lane >> 3;  // 0..7
  // stage rows = j*32 + w*8 + srow -> key(row) = (row&7)^((row>>3)&3) = srow^w
  const int sgc = ((lane & 7) ^ srow ^ w) * 8;

  auto stA = [&](int buf, int kt, int j) {
    const int r = j * 32 + w * 8 + srow;
    GLDS16(A2 + (long)(bm * 128 + r) * 6144 + kt * 64 + sgc,
           &uA[buf * 8192 + (j * 32 + w * 8) * 64]);
  };
  auto stB = [&](int buf, int kt, int j) {
    const int r = j * 32 + w * 8 + srow;
    GLDS16(B2 + (long)(bn * 192 + r) * 6144 + kt * 64 + sgc,
           &uB[buf * 12288 + (j * 32 + w * 8) * 64]);
  };

  f32x16 acc[2][3];
#pragma unroll
  for (int m = 0; m < 2; ++m)
#pragma unroll
    for (int n = 0; n < 3; ++n)
#pragma unroll
      for (int j = 0; j < 16; ++j) acc[m][n][j] = 0.f;

  // prologue
  stA(0, 0, 0); stA(0, 0, 1); stA(0, 0, 2); stA(0, 0, 3);
  stB(0, 0, 0); stB(0, 0, 1); stB(0, 0, 2);
  stB(0, 0, 3); stB(0, 0, 4); stB(0, 0, 5);
  __syncthreads();

  const int aRow0 = wm * 64 + l31;
  const int bRow0 = wn * 96 + l31;
  const int rk = (lane & 7) ^ ((lane >> 3) & 3);

#define CSLOT(KS, PL) ((((KS)*2 + l5 + (PL)*4) ^ rk) * 8)
#define RD_PH(KS)                                                          \
  _Pragma("unroll") for (int n = 0; n < 3; ++n) {                          \
    const int off = (bRow0 + n * 32) * 64;                                 \
    b[n][0] = ld16(&LB[off + CSLOT(KS, 0)]);                               \
    b[n][1] = ld16(&LB[off + CSLOT(KS, 1)]);                               \
  }                                                                        \
  _Pragma("unroll") for (int m = 0; m < 2; ++m) {                          \
    const int off = (aRow0 + m * 32) * 64;                                 \
    a[m][0] = ld16(&LA[off + CSLOT(KS, 0)]);                               \
    a[m][1] = ld16(&LA[off + CSLOT(KS, 1)]);                               \
  }
#define DO_MFMA3()                                                         \
  __builtin_amdgcn_s_setprio(1);                                           \
  _Pragma("unroll") for (int m = 0; m < 2; ++m)                            \
  _Pragma("unroll") for (int n = 0; n < 3; ++n) {                          \
    acc[m][n] = MFMA32(a[m][0], b[n][0], acc[m][n]);                       \
    acc[m][n] = MFMA32(a[m][0], b[n][1], acc[m][n]);                       \
    acc[m][n] = MFMA32(a[m][1], b[n][0], acc[m][n]);                       \
  }                                                                        \
  __builtin_amdgcn_s_setprio(0);
#define PH_SYNC()                                                          \
  __builtin_amdgcn_s_barrier();                                            \
  asm volatile("s_waitcnt lgkmcnt(0)" ::: "memory");                       \
  __builtin_amdgcn_sched_barrier(0);

  for (int t = 0; t < NT; ++t) {
    const int cur = t & 1;
    const int nxt = cur ^ 1;
    const u16* LA = &uA[cur * 8192];
    const u16* LB = &uB[cur * 12288];
    bf16x8 a[2][2], b[3][2];
    RD_PH(0);
    if (t + 1 < NT) {
      stA(nxt, t + 1, 0); stA(nxt, t + 1, 1);
      stA(nxt, t + 1, 2); stA(nxt, t + 1, 3);
      stB(nxt, t + 1, 0); stB(nxt, t + 1, 1); stB(nxt, t + 1, 2);
      stB(nxt, t + 1, 3); stB(nxt, t + 1, 4); stB(nxt, t + 1, 5);
    }
    PH_SYNC();
    DO_MFMA3();
    __builtin_amdgcn_s_barrier();
    RD_PH(1);
    PH_SYNC();
    DO_MFMA3();
    asm volatile("s_waitcnt vmcnt(0)" ::: "memory");
    __builtin_amdgcn_s_barrier();
  }
#undef CSLOT
#undef RD_PH
#undef DO_MFMA3
#undef PH_SYNC

  // epilogue. C/D: col=lane&31, row=(reg&3)+8*(reg>>2)+4*(lane>>5) (m101)
  if (MODE == 1 || (MODE == 2 && bn < 16)) {
#pragma unroll
    for (int mf = 0; mf < 2; ++mf)
#pragma unroll
      for (int nf = 0; nf < 3; ++nf) {
        const int col = bn * 192 + wn * 96 + nf * 32 + l31;
#pragma unroll
        for (int reg = 0; reg < 16; ++reg) {
          const int rif = (reg & 3) + 8 * (reg >> 2) + 4 * l5;
          const long row = (long)bm * 128 + wm * 64 + mf * 32 + rif;
          const float v = acc[mf][nf][reg];
          if (MODE == 1) {
            Cf[row * N + col] = v + bias[col];
          } else {  // compact Q2 [4096][6144]
            const long idx = row * 6144 + (col >> 5) * 64 + (col & 31);
            u16 h, l;
            split2(v, h, l);
            C2[idx] = h;
            C2[idx + 32] = l;
          }
        }
      }
  } else if (MODE == 2) {
    // K/V packed epilogue via LDS transpose. P[pl][64 s][200] (51.2 KB).
    const bool isV = (bn >= 32);
    const int hd0 = (bn - (isV ? 32 : 16)) * 2;  // first of 2 heads
    const int b = (bm * 128) >> 11;
    const int s_loc = (bm * 128) & 2047;
    u16* const P = shm;
    u16* const dst = isV ? Vp : Kp;
#pragma unroll
    for (int hf = 0; hf < 2; ++hf) {
      __syncthreads();
      if (wm == hf) {  // this wave owns rows hf*64 .. hf*64+63
#pragma unroll
        for (int mf = 0; mf < 2; ++mf)
#pragma unroll
          for (int nf = 0; nf < 3; ++nf)
#pragma unroll
            for (int reg = 0; reg < 16; ++reg) {
              const int rif = (reg & 3) + 8 * (reg >> 2) + 4 * l5;
              const int row_l = mf * 32 + rif;                // 0..63
              const int col_l = wn * 96 + nf * 32 + l31;      // 0..191
              u16 h, l;
              split2(acc[mf][nf][reg], h, l);
              P[row_l * 200 + col_l] = h;
              P[(64 + row_l) * 200 + col_l] = l;
            }
      }
      __syncthreads();
      const int lr = lane & 15, lg = lane >> 4;
      if (!isV) {
        // 48 records: ri = ((hh*3+c)*4+kbi)*2+pl; rec covers 16s x 32d.
#pragma unroll
        for (int i = 0; i < 12; ++i) {
          const int ri = w * 12 + i;
          const int pl = ri & 1;
          const int kbi = (ri >> 1) & 3;
          const int c = (ri >> 3) % 3;
          const int hh = ri / 24;
          const bf16x8 v =
              ld16(&P[(pl * 64 + kbi * 16 + lr) * 200 + hh * 96 + c * 32 + lg * 8]);
          const int hl = b * 32 + hd0 + hh;
          const int kbg = ((s_loc + hf * 64) >> 4) + kbi;
          const long rec3 = ((long)hl * 128 + kbg) * 3 + c;
          *reinterpret_cast<bf16x8*>(dst + (rec3 * 2 + pl) * 512 + lane * 8) = v;
        }
      } else {
        // 48 records: ri = ((hh*6+n)*2+kq)*2+pl; lane holds V^T[n*16+lr][..s..]
#pragma unroll
        for (int i = 0; i < 12; ++i) {
          const int ri = w * 12 + i;
          const int pl = ri & 1;
          const int kq = (ri >> 1) & 1;
          const int n = (ri >> 2) % 6;
          const int hh = ri / 24;
          bf16x8 v;
#pragma unroll
          for (int e = 0; e < 8; ++e)
            v[e] = (short)P[(pl * 64 + kq * 32 + lg * 8 + e) * 200 + hh * 96 + n * 16 + lr];
          const int hl = b * 32 + hd0 + hh;
          const int kqg = ((s_loc + hf * 64) >> 5) + kq;
          const long rec = (((long)hl * 6 + n) * 64 + kqg) * 2 + pl;
          *reinterpret_cast<bf16x8*>(dst + rec * 512 + lane * 8) = v;
        }
      }
    }
  }
}

// ------------------------------------------------------------- attention ---
// r20: 32 q-rows/wave (2 frags); KV tile = 64 rows/iter (32 iters, halved
// per-iter fixed costs). K LDS-staged double-buffered (24 records/iter);
// V^T direct-from-global, prefetched at half start (hidden under QK^T).
// launch_bounds(256,2), LDS 64 KB -> 2 blocks/CU. Max-free softmax.
__global__ __launch_bounds__(256, 2) void attn_kernel(
    const u16* __restrict__ Q2,
    const u16* __restrict__ Kp, const u16* __restrict__ Vp,
    u16* __restrict__ AO2) {
  __shared__ u16 kv[2][24 * 512];   // 48 KB: K records for 64 kv rows
  __shared__ u16 pb[4][2][2][512];  // 16 KB: [wave][frag][plane]
  const int lane = threadIdx.x & 63;
  const int wv = threadIdx.x >> 6;
  const int lr = lane & 15, lg = lane >> 4;

  const int nwg = gridDim.x;
  const int bid = blockIdx.x;
  const int wg = (bid & 7) * (nwg >> 3) + (bid >> 3);  // XCD swizzle
  const int hl = wg >> 4;    // b*32 + head
  const int qblk = wg & 15;  // 16 q-blocks of 128 rows
  const int b = hl >> 5;
  const int q0 = qblk * 128 + wv * 32;

  bf16x8 qh[2][3], ql[2][3];
#pragma unroll
  for (int f = 0; f < 2; ++f) {
    const long qofs =
        ((long)(b * 2048 + q0 + f * 16 + lr)) * 6144 + ((hl & 31) * 3) * 64 + lg * 8;
#pragma unroll
    for (int c = 0; c < 3; ++c) {
      qh[f][c] = ld16(Q2 + qofs + c * 64);
      ql[f][c] = ld16(Q2 + qofs + c * 64 + 32);
    }
  }

  f32x4 o_acc[2][6];
#pragma unroll
  for (int f = 0; f < 2; ++f)
#pragma unroll
    for (int n = 0; n < 6; ++n)
#pragma unroll
      for (int j = 0; j < 4; ++j) o_acc[f][n][j] = 0.f;
  float lsum[2][4] = {{0.f, 0.f, 0.f, 0.f}, {0.f, 0.f, 0.f, 0.f}};

  const float scale = 0.10206207261596577f;  // 96^-0.5

  // stage 24 K records for iter `it` (64 kv rows); 6 glds per wave.
  // Kp record linear index = hl*768 + kb*6 + c*2 + pl; kb = it*4 + r/6.
  auto stage = [&](int nb, int it) {
    const long base = ((long)hl * 768 + (long)it * 24) * 512;
#pragma unroll
    for (int j = 0; j < 6; ++j) {
      const int r = wv * 6 + j;
      GLDS16(Kp + base + (long)r * 512 + lane * 8, &kv[nb][r * 512]);
    }
  };

  stage(0, 0);
  __syncthreads();

  for (int it = 0; it < 32; ++it) {
    const int nb = it & 1;
    if (it < 31) stage(nb ^ 1, it + 1);
#pragma unroll
    for (int h = 0; h < 2; ++h) {
      const u16* L = kv[nb] + h * (12 * 512);

      // V prefetch for this half (L2-hot); consumed after QK^T
      bf16x8 vh[6], vl[6];
#pragma unroll
      for (int n = 0; n < 6; ++n) {
        const long ro =
            ((((long)(hl * 6 + n)) * 64 + (it * 2 + h)) * 2) * 512 + lane * 8;
        vh[n] = ld16(Vp + ro);
        vl[n] = ld16(Vp + ro + 512);
      }

      // K fragment loads (shared by both q-frags)
      bf16x8 kh0[3], kl0[3], kh1[3], kl1[3];
#pragma unroll
      for (int c = 0; c < 3; ++c) {
        kh0[c] = ld16(L + (c * 2 + 0) * 512 + lane * 8);
        kl0[c] = ld16(L + (c * 2 + 1) * 512 + lane * 8);
        kh1[c] = ld16(L + (6 + c * 2 + 0) * 512 + lane * 8);
        kl1[c] = ld16(L + (6 + c * 2 + 1) * 512 + lane * 8);
      }

      bf16x8 pah[2], pal[2];
#pragma unroll
      for (int f = 0; f < 2; ++f) {
        f32x4 s0, s1;
#pragma unroll
        for (int j = 0; j < 4; ++j) { s0[j] = 0.f; s1[j] = 0.f; }
#pragma unroll
        for (int c = 0; c < 3; ++c) {
          s0 = MFMA(qh[f][c], kh0[c], s0);
          s1 = MFMA(qh[f][c], kh1[c], s1);
          s0 = MFMA(qh[f][c], kl0[c], s0);
          s1 = MFMA(qh[f][c], kl1[c], s1);
          s0 = MFMA(ql[f][c], kh0[c], s0);
          s1 = MFMA(ql[f][c], kh1[c], s1);
        }
        u16* pbh = pb[wv][f][0];
        u16* pbl = pb[wv][f][1];
#pragma unroll
        for (int j = 0; j < 4; ++j) {
          const float p0 = __expf(fmaf(s0[j], scale, -12.f));
          const float p1 = __expf(fmaf(s1[j], scale, -12.f));
          lsum[f][j] += p0 + p1;
          const int r = lg * 4 + j;
          const int key = j ^ lg;
          u16 hh, ll;
          split2(p0, hh, ll);
          const int a0 = r * 32 + ((((lr >> 3) ^ key) & 3) << 3) + (lr & 7);
          pbh[a0] = hh;
          pbl[a0] = ll;
          split2(p1, hh, ll);
          const int a1 = r * 32 + ((((2 + (lr >> 3)) ^ key) & 3) << 3) + (lr & 7);
          pbh[a1] = hh;
          pbl[a1] = ll;
        }
        const int rkey = (lr & 3) ^ (lr >> 2);
        const int ra = lr * 32 + (((lg ^ rkey) & 3) << 3);
        pah[f] = ld16(&pbh[ra]);
        pal[f] = ld16(&pbl[ra]);
      }

#pragma unroll
      for (int n = 0; n < 6; ++n)
#pragma unroll
        for (int f = 0; f < 2; ++f) {
          o_acc[f][n] = MFMA(pah[f], vh[n], o_acc[f][n]);
          o_acc[f][n] = MFMA(pah[f], vl[n], o_acc[f][n]);
          o_acc[f][n] = MFMA(pal[f], vh[n], o_acc[f][n]);
        }
    }
    __syncthreads();
  }

#pragma unroll
  for (int f = 0; f < 2; ++f) {
    float inv[4];
#pragma unroll
    for (int j = 0; j < 4; ++j) {
      float rs = lsum[f][j];
#pragma unroll
      for (int mk = 1; mk < 16; mk <<= 1) rs += __shfl_xor(rs, mk);
      inv[j] = 1.f / rs;
    }
#pragma unroll
    for (int n = 0; n < 6; ++n)
#pragma unroll
      for (int j = 0; j < 4; ++j) {
        const long row = (long)(b * 2048 + q0 + f * 16 + lg * 4 + j);
        const long idx =
            row * 6144 + ((hl & 31) * 3 + (n >> 1)) * 64 + (n & 1) * 16 + lr;
        u16 h, l;
        split2(o_acc[f][n][j] * inv[j], h, l);
        AO2[idx] = h;
        AO2[idx + 32] = l;
      }
  }
}

// ---------------------------------------------------------------- launch ---
extern "C" void kernel_launch(void* const* d_in, const int* in_sizes, int n_in,
                              void* d_out, int out_size, void* d_ws, size_t ws_size,
                              hipStream_t stream) {
  const float* x = (const float*)d_in[0];     // [4096][3072]
  const float* wqkv = (const float*)d_in[1];  // [9216][3072]
  const float* wo = (const float*)d_in[2];    // [3072][3072]
  const float* bo = (const float*)d_in[3];    // [3072]
  float* out = (float*)d_out;                 // [4096][3072]
  char* ws = (char*)d_ws;

  const size_t E_X = (size_t)4096 * 3072;
  const size_t E_WQ = (size_t)9216 * 3072;
  const size_t E_WO = (size_t)3072 * 3072;

  // layout (bytes): X2[4E_X] | W2[4E_WQ] | Q2[4E_X] | KP[4E_X] | VP[4E_X]
  // after GEMM1, W2 region is dead -> AO2 (4E_X) + WO2 (4E_WO) fit inside.
  u16* X2 = (u16*)ws;
  char* W0 = ws + 4 * E_X;
  u16* W2 = (u16*)W0;
  u16* Q2 = (u16*)(W0 + 4 * E_WQ);
  u16* KP = Q2 + 2 * E_X;
  u16* VP = KP + 2 * E_X;
  u16* AO2 = (u16*)W0;
  u16* WO2 = (u16*)(W0 + 4 * E_X);

  const size_t need = 4 * (4 * E_X + E_WQ);  // 314.6 MB
  if (ws_size < need) return;

  split_kernel<<<6144, 256, 0, stream>>>(x, X2, (long)E_X);
  split_kernel<<<13824, 256, 0, stream>>>(wqkv, W2, (long)E_WQ);
  gemm32<2><<<1536, 256, 0, stream>>>(X2, W2, 4096, 9216, Q2, KP, VP,
                                      nullptr, nullptr);
  split_kernel<<<4608, 256, 0, stream>>>(wo, WO2, (long)E_WO);
  attn_kernel<<<1024, 256, 0, stream>>>(Q2, KP, VP, AO2);
  gemm32<1><<<512, 256, 0, stream>>>(AO2, WO2, 4096, 3072, nullptr, nullptr,
                                     nullptr, out, bo);
}

// Round 21
// 1156.262 us; speedup vs baseline: 1.0740x; 1.0740x over previous
//
#include <hip/hip_runtime.h>
#include <math.h>

// fp32 attention layer via split-bf16 (hi/lo) 3-term MFMA emulation.
// Interleaved storage: [row][(col/32)*64 + col%32 + plane*32].
// r21: attn reverted to r16 (best measured); all three splits fused into
// ONE launch (block-range dispatch; WO2 moved to its own region so the
// wo split can run pre-GEMM1). GEMM: r16 (128x192, 2 blk/CU, fused pack).

typedef unsigned int u32;
typedef unsigned short u16;
typedef __attribute__((ext_vector_type(8))) short bf16x8;
typedef __attribute__((ext_vector_type(4))) float f32x4;
typedef __attribute__((ext_vector_type(16))) float f32x16;

#define MFMA(a, b, c) __builtin_amdgcn_mfma_f32_16x16x32_bf16((a), (b), (c), 0, 0, 0)
#define MFMA32(a, b, c) __builtin_amdgcn_mfma_f32_32x32x16_bf16((a), (b), (c), 0, 0, 0)

#define GLDS16(g, l) __builtin_amdgcn_global_load_lds( \
    (const __attribute__((address_space(1))) u32*)(g), \
    (__attribute__((address_space(3))) u32*)(l), 16, 0, 0)

__device__ __forceinline__ u16 f2bf(float f) {
  u32 u = __builtin_bit_cast(u32, f);
  return (u16)((u + 0x7fffu + ((u >> 16) & 1u)) >> 16);  // RNE
}
__device__ __forceinline__ float bf2f(u16 h) {
  u32 u = ((u32)h) << 16;
  return __builtin_bit_cast(float, u);
}
__device__ __forceinline__ void split2(float f, u16& h, u16& l) {
  h = f2bf(f);
  l = f2bf(f - bf2f(h));
}
__device__ __forceinline__ bf16x8 ld16(const u16* p) {
  return *reinterpret_cast<const bf16x8*>(p);
}

// ---------------------------------------------------------------- split ----
// Fused: blocks [0,6144) x->X2, [6144,19968) wqkv->W2, [19968,24576) wo->WO2.
// fp32 [R][3072] -> interleaved hi/lo u16 [R][6144], 8 floats/thread.
__global__ void split_fused(const float* __restrict__ x, u16* __restrict__ X2,
                            const float* __restrict__ wq, u16* __restrict__ W2,
                            const float* __restrict__ wo, u16* __restrict__ WO2) {
  const float* src;
  u16* dst;
  int blk = blockIdx.x;
  if (blk < 6144) {
    src = x; dst = X2;
  } else if (blk < 19968) {
    src = wq; dst = W2; blk -= 6144;
  } else {
    src = wo; dst = WO2; blk -= 19968;
  }
  const long i = ((long)blk * 256 + threadIdx.x) * 8;
  const float4 v0 = *reinterpret_cast<const float4*>(src + i);
  const float4 v1 = *reinterpret_cast<const float4*>(src + i + 4);
  const u32 i32 = (u32)i;
  const u32 row = i32 / 3072u;
  const u32 col = i32 - row * 3072u;
  const long base = (long)row * 6144 + (col >> 5) * 64 + (col & 31);
  bf16x8 hv, lv;
  u16 h, l;
  split2(v0.x, h, l); hv[0] = (short)h; lv[0] = (short)l;
  split2(v0.y, h, l); hv[1] = (short)h; lv[1] = (short)l;
  split2(v0.z, h, l); hv[2] = (short)h; lv[2] = (short)l;
  split2(v0.w, h, l); hv[3] = (short)h; lv[3] = (short)l;
  split2(v1.x, h, l); hv[4] = (short)h; lv[4] = (short)l;
  split2(v1.y, h, l); hv[5] = (short)h; lv[5] = (short)l;
  split2(v1.z, h, l); hv[6] = (short)h; lv[6] = (short)l;
  split2(v1.w, h, l); hv[7] = (short)h; lv[7] = (short)l;
  *reinterpret_cast<bf16x8*>(dst + base) = hv;
  *reinterpret_cast<bf16x8*>(dst + base + 32) = lv;
}

// --------------------------------------- 128x192 3-term GEMM, 32x32x16 ----
// C = Ah*Bh^T + Ah*Bl^T + Al*Bh^T; A2[M][6144], B2[N][6144] interleaved.
// K=3072 -> NT=96 tiles of 32 (2 MFMA k-subs of 16). 4 waves (2M x 2N),
// wave tile 64x96, acc 6 x f32x16 = 96 VGPR. LDS 80 KiB -> 2 blocks/CU.
// MODE 1: fp32 C + bias (o_proj). MODE 2: QKV epilogue -- bn<16: compact
// Q2 [4096][6144]; bn 16..31: K packed records; bn>=32: V^T packed records
// (LDS-transpose via P[2][64][200], reusing staging LDS post-loop).
template <int MODE>
__global__ __launch_bounds__(256, 2) void gemm32(
    const u16* __restrict__ A2, const u16* __restrict__ B2,
    int M, int N, u16* __restrict__ C2, u16* __restrict__ Kp,
    u16* __restrict__ Vp, float* __restrict__ Cf, const float* __restrict__ bias) {
  constexpr int NT = 96;
  __shared__ u16 shm[2 * 128 * 64 + 2 * 192 * 64];  // 80 KiB
  u16* const uA = shm;                  // 2 x 128x64
  u16* const uB = shm + 2 * 128 * 64;   // 2 x 192x64
  const int tid = threadIdx.x;
  const int lane = tid & 63;
  const int w = tid >> 6;             // 0..3
  const int wm = w >> 1, wn = w & 1;  // 2M x 2N
  const int l31 = lane & 31;
  const int l5 = lane >> 5;

  const int mt = M >> 7;  // 128-row tiles
  const int nwg = gridDim.x;
  const int bid = blockIdx.x;
  const int wg = (bid & 7) * (nwg >> 3) + (bid >> 3);  // XCD swizzle (nwg%8==0)
  const int bm = wg % mt, bn = wg / mt;

  const int srow = lane >> 3;  // 0..7
  // stage rows = j*32 + w*8 + srow -> key(row) = (row&7)^((row>>3)&3) = srow^w
  const int sgc = ((lane & 7) ^ srow ^ w) * 8;

  auto stA = [&](int buf, int kt, int j) {
    const int r = j * 32 + w * 8 + srow;
    GLDS16(A2 + (long)(bm * 128 + r) * 6144 + kt * 64 + sgc,
           &uA[buf * 8192 + (j * 32 + w * 8) * 64]);
  };
  auto stB = [&](int buf, int kt, int j) {
    const int r = j * 32 + w * 8 + srow;
    GLDS16(B2 + (long)(bn * 192 + r) * 6144 + kt * 64 + sgc,
           &uB[buf * 12288 + (j * 32 + w * 8) * 64]);
  };

  f32x16 acc[2][3];
#pragma unroll
  for (int m = 0; m < 2; ++m)
#pragma unroll
    for (int n = 0; n < 3; ++n)
#pragma unroll
      for (int j = 0; j < 16; ++j) acc[m][n][j] = 0.f;

  // prologue
  stA(0, 0, 0); stA(0, 0, 1); stA(0, 0, 2); stA(0, 0, 3);
  stB(0, 0, 0); stB(0, 0, 1); stB(0, 0, 2);
  stB(0, 0, 3); stB(0, 0, 4); stB(0, 0, 5);
  __syncthreads();

  const int aRow0 = wm * 64 + l31;
  const int bRow0 = wn * 96 + l31;
  const int rk = (lane & 7) ^ ((lane >> 3) & 3);

#define CSLOT(KS, PL) ((((KS)*2 + l5 + (PL)*4) ^ rk) * 8)
#define RD_PH(KS)                                                          \
  _Pragma("unroll") for (int n = 0; n < 3; ++n) {                          \
    const int off = (bRow0 + n * 32) * 64;                                 \
    b[n][0] = ld16(&LB[off + CSLOT(KS, 0)]);                               \
    b[n][1] = ld16(&LB[off + CSLOT(KS, 1)]);                               \
  }                                                                        \
  _Pragma("unroll") for (int m = 0; m < 2; ++m) {                          \
    const int off = (aRow0 + m * 32) * 64;                                 \
    a[m][0] = ld16(&LA[off + CSLOT(KS, 0)]);                               \
    a[m][1] = ld16(&LA[off + CSLOT(KS, 1)]);                               \
  }
#define DO_MFMA3()                                                         \
  __builtin_amdgcn_s_setprio(1);                                           \
  _Pragma("unroll") for (int m = 0; m < 2; ++m)                            \
  _Pragma("unroll") for (int n = 0; n < 3; ++n) {                          \
    acc[m][n] = MFMA32(a[m][0], b[n][0], acc[m][n]);                       \
    acc[m][n] = MFMA32(a[m][0], b[n][1], acc[m][n]);                       \
    acc[m][n] = MFMA32(a[m][1], b[n][0], acc[m][n]);                       \
  }                                                                        \
  __builtin_amdgcn_s_setprio(0);
#define PH_SYNC()                                                          \
  __builtin_amdgcn_s_barrier();                                            \
  asm volatile("s_waitcnt lgkmcnt(0)" ::: "memory");                       \
  __builtin_amdgcn_sched_barrier(0);

  for (int t = 0; t < NT; ++t) {
    const int cur = t & 1;
    const int nxt = cur ^ 1;
    const u16* LA = &uA[cur * 8192];
    const u16* LB = &uB[cur * 12288];
    bf16x8 a[2][2], b[3][2];
    RD_PH(0);
    if (t + 1 < NT) {
      stA(nxt, t + 1, 0); stA(nxt, t + 1, 1);
      stA(nxt, t + 1, 2); stA(nxt, t + 1, 3);
      stB(nxt, t + 1, 0); stB(nxt, t + 1, 1); stB(nxt, t + 1, 2);
      stB(nxt, t + 1, 3); stB(nxt, t + 1, 4); stB(nxt, t + 1, 5);
    }
    PH_SYNC();
    DO_MFMA3();
    __builtin_amdgcn_s_barrier();
    RD_PH(1);
    PH_SYNC();
    DO_MFMA3();
    asm volatile("s_waitcnt vmcnt(0)" ::: "memory");
    __builtin_amdgcn_s_barrier();
  }
#undef CSLOT
#undef RD_PH
#undef DO_MFMA3
#undef PH_SYNC

  // epilogue. C/D: col=lane&31, row=(reg&3)+8*(reg>>2)+4*(lane>>5) (m101)
  if (MODE == 1 || (MODE == 2 && bn < 16)) {
#pragma unroll
    for (int mf = 0; mf < 2; ++mf)
#pragma unroll
      for (int nf = 0; nf < 3; ++nf) {
        const int col = bn * 192 + wn * 96 + nf * 32 + l31;
#pragma unroll
        for (int reg = 0; reg < 16; ++reg) {
          const int rif = (reg & 3) + 8 * (reg >> 2) + 4 * l5;
          const long row = (long)bm * 128 + wm * 64 + mf * 32 + rif;
          const float v = acc[mf][nf][reg];
          if (MODE == 1) {
            Cf[row * N + col] = v + bias[col];
          } else {  // compact Q2 [4096][6144]
            const long idx = row * 6144 + (col >> 5) * 64 + (col & 31);
            u16 h, l;
            split2(v, h, l);
            C2[idx] = h;
            C2[idx + 32] = l;
          }
        }
      }
  } else if (MODE == 2) {
    // K/V packed epilogue via LDS transpose. P[pl][64 s][200] (51.2 KB).
    const bool isV = (bn >= 32);
    const int hd0 = (bn - (isV ? 32 : 16)) * 2;  // first of 2 heads
    const int b = (bm * 128) >> 11;
    const int s_loc = (bm * 128) & 2047;
    u16* const P = shm;
    u16* const dst = isV ? Vp : Kp;
#pragma unroll
    for (int hf = 0; hf < 2; ++hf) {
      __syncthreads();
      if (wm == hf) {  // this wave owns rows hf*64 .. hf*64+63
#pragma unroll
        for (int mf = 0; mf < 2; ++mf)
#pragma unroll
          for (int nf = 0; nf < 3; ++nf)
#pragma unroll
            for (int reg = 0; reg < 16; ++reg) {
              const int rif = (reg & 3) + 8 * (reg >> 2) + 4 * l5;
              const int row_l = mf * 32 + rif;                // 0..63
              const int col_l = wn * 96 + nf * 32 + l31;      // 0..191
              u16 h, l;
              split2(acc[mf][nf][reg], h, l);
              P[row_l * 200 + col_l] = h;
              P[(64 + row_l) * 200 + col_l] = l;
            }
      }
      __syncthreads();
      const int lr = lane & 15, lg = lane >> 4;
      if (!isV) {
        // 48 records: ri = ((hh*3+c)*4+kbi)*2+pl; rec covers 16s x 32d.
#pragma unroll
        for (int i = 0; i < 12; ++i) {
          const int ri = w * 12 + i;
          const int pl = ri & 1;
          const int kbi = (ri >> 1) & 3;
          const int c = (ri >> 3) % 3;
          const int hh = ri / 24;
          const bf16x8 v =
              ld16(&P[(pl * 64 + kbi * 16 + lr) * 200 + hh * 96 + c * 32 + lg * 8]);
          const int hl = b * 32 + hd0 + hh;
          const int kbg = ((s_loc + hf * 64) >> 4) + kbi;
          const long rec3 = ((long)hl * 128 + kbg) * 3 + c;
          *reinterpret_cast<bf16x8*>(dst + (rec3 * 2 + pl) * 512 + lane * 8) = v;
        }
      } else {
        // 48 records: ri = ((hh*6+n)*2+kq)*2+pl; lane holds V^T[n*16+lr][..s..]
#pragma unroll
        for (int i = 0; i < 12; ++i) {
          const int ri = w * 12 + i;
          const int pl = ri & 1;
          const int kq = (ri >> 1) & 1;
          const int n = (ri >> 2) % 6;
          const int hh = ri / 24;
          bf16x8 v;
#pragma unroll
          for (int e = 0; e < 8; ++e)
            v[e] = (short)P[(pl * 64 + kq * 32 + lg * 8 + e) * 200 + hh * 96 + n * 16 + lr];
          const int hl = b * 32 + hd0 + hh;
          const int kqg = ((s_loc + hf * 64) >> 5) + kq;
          const long rec = (((long)hl * 6 + n) * 64 + kqg) * 2 + pl;
          *reinterpret_cast<bf16x8*>(dst + rec * 512 + lane * 8) = v;
        }
      }
    }
  }
}

// ------------------------------------------------------------- attention ---
// r16 version (best-measured): 32 q-rows/wave (2 frags), block = 128
// q-rows; K/V LDS-staged (shared), launch_bounds(256,2). Q from compact
// Q2 [4096][6144]. Max-free softmax.
__global__ __launch_bounds__(256, 2) void attn_kernel(
    const u16* __restrict__ Q2,
    const u16* __restrict__ Kp, const u16* __restrict__ Vp,
    u16* __restrict__ AO2) {
  __shared__ u16 kv[2][24 * 512];   // 48 KB
  __shared__ u16 pb[4][2][2][512];  // 16 KB: [wave][frag][plane]
  const int lane = threadIdx.x & 63;
  const int wv = threadIdx.x >> 6;
  const int lr = lane & 15, lg = lane >> 4;

  const int nwg = gridDim.x;
  const int bid = blockIdx.x;
  const int wg = (bid & 7) * (nwg >> 3) + (bid >> 3);  // XCD swizzle
  const int hl = wg >> 4;    // b*32 + head
  const int qblk = wg & 15;  // 16 q-blocks of 128 rows
  const int b = hl >> 5;
  const int q0 = qblk * 128 + wv * 32;

  bf16x8 qh[2][3], ql[2][3];
#pragma unroll
  for (int f = 0; f < 2; ++f) {
    const long qofs =
        ((long)(b * 2048 + q0 + f * 16 + lr)) * 6144 + ((hl & 31) * 3) * 64 + lg * 8;
#pragma unroll
    for (int c = 0; c < 3; ++c) {
      qh[f][c] = ld16(Q2 + qofs + c * 64);
      ql[f][c] = ld16(Q2 + qofs + c * 64 + 32);
    }
  }

  f32x4 o_acc[2][6];
#pragma unroll
  for (int f = 0; f < 2; ++f)
#pragma unroll
    for (int n = 0; n < 6; ++n)
#pragma unroll
      for (int j = 0; j < 4; ++j) o_acc[f][n][j] = 0.f;
  float lsum[2][4] = {{0.f, 0.f, 0.f, 0.f}, {0.f, 0.f, 0.f, 0.f}};

  const float scale = 0.10206207261596577f;  // 96^-0.5

  auto stage = [&](int nb, int it) {
    const long kbase = ((long)hl * 768 + (long)it * 12) * 512;
    const long vbase = ((long)hl * 768 + (long)it * 2) * 512;
#pragma unroll
    for (int j = 0; j < 6; ++j) {
      const int r = wv * 6 + j;
      const u16* src;
      if (r < 12) {
        const int tt = r / 6, rc = r % 6;
        src = Kp + kbase + ((long)(tt * 6 + rc)) * 512 + lane * 8;
      } else {
        const int r2 = r - 12;
        src = Vp + vbase + ((long)((r2 >> 1) * 128 + (r2 & 1))) * 512 + lane * 8;
      }
      GLDS16(src, &kv[nb][r * 512]);
    }
  };

  stage(0, 0);
  __syncthreads();

  for (int it = 0; it < 64; ++it) {
    const int nb = it & 1;
    if (it < 63) stage(nb ^ 1, it + 1);
    const u16* L = kv[nb];

    bf16x8 kh0[3], kl0[3], kh1[3], kl1[3];
#pragma unroll
    for (int c = 0; c < 3; ++c) {
      kh0[c] = ld16(L + (c * 2 + 0) * 512 + lane * 8);
      kl0[c] = ld16(L + (c * 2 + 1) * 512 + lane * 8);
      kh1[c] = ld16(L + (6 + c * 2 + 0) * 512 + lane * 8);
      kl1[c] = ld16(L + (6 + c * 2 + 1) * 512 + lane * 8);
    }

    bf16x8 pah[2], pal[2];
#pragma unroll
    for (int f = 0; f < 2; ++f) {
      f32x4 s0, s1;
#pragma unroll
      for (int j = 0; j < 4; ++j) { s0[j] = 0.f; s1[j] = 0.f; }
#pragma unroll
      for (int c = 0; c < 3; ++c) {
        s0 = MFMA(qh[f][c], kh0[c], s0);
        s1 = MFMA(qh[f][c], kh1[c], s1);
        s0 = MFMA(qh[f][c], kl0[c], s0);
        s1 = MFMA(qh[f][c], kl1[c], s1);
        s0 = MFMA(ql[f][c], kh0[c], s0);
        s1 = MFMA(ql[f][c], kh1[c], s1);
      }
      u16* pbh = pb[wv][f][0];
      u16* pbl = pb[wv][f][1];
#pragma unroll
      for (int j = 0; j < 4; ++j) {
        const float p0 = __expf(fmaf(s0[j], scale, -12.f));
        const float p1 = __expf(fmaf(s1[j], scale, -12.f));
        lsum[f][j] += p0 + p1;
        const int r = lg * 4 + j;
        const int key = j ^ lg;
        u16 h, l;
        split2(p0, h, l);
        const int a0 = r * 32 + ((((lr >> 3) ^ key) & 3) << 3) + (lr & 7);
        pbh[a0] = h;
        pbl[a0] = l;
        split2(p1, h, l);
        const int a1 = r * 32 + ((((2 + (lr >> 3)) ^ key) & 3) << 3) + (lr & 7);
        pbh[a1] = h;
        pbl[a1] = l;
      }
      const int rkey = (lr & 3) ^ (lr >> 2);
      const int ra = lr * 32 + (((lg ^ rkey) & 3) << 3);
      pah[f] = ld16(&pbh[ra]);
      pal[f] = ld16(&pbl[ra]);
    }

#pragma unroll
    for (int n = 0; n < 6; ++n) {
      const bf16x8 vh = ld16(L + (12 + n * 2 + 0) * 512 + lane * 8);
      const bf16x8 vl = ld16(L + (12 + n * 2 + 1) * 512 + lane * 8);
#pragma unroll
      for (int f = 0; f < 2; ++f) {
        o_acc[f][n] = MFMA(pah[f], vh, o_acc[f][n]);
        o_acc[f][n] = MFMA(pah[f], vl, o_acc[f][n]);
        o_acc[f][n] = MFMA(pal[f], vh, o_acc[f][n]);
      }
    }
    __syncthreads();
  }

#pragma unroll
  for (int f = 0; f < 2; ++f) {
    float inv[4];
#pragma unroll
    for (int j = 0; j < 4; ++j) {
      float rs = lsum[f][j];
#pragma unroll
      for (int mk = 1; mk < 16; mk <<= 1) rs += __shfl_xor(rs, mk);
      inv[j] = 1.f / rs;
    }
#pragma unroll
    for (int n = 0; n < 6; ++n)
#pragma unroll
      for (int j = 0; j < 4; ++j) {
        const long row = (long)(b * 2048 + q0 + f * 16 + lg * 4 + j);
        const long idx =
            row * 6144 + ((hl & 31) * 3 + (n >> 1)) * 64 + (n & 1) * 16 + lr;
        u16 h, l;
        split2(o_acc[f][n][j] * inv[j], h, l);
        AO2[idx] = h;
        AO2[idx + 32] = l;
      }
  }
}

// ---------------------------------------------------------------- launch ---
extern "C" void kernel_launch(void* const* d_in, const int* in_sizes, int n_in,
                              void* d_out, int out_size, void* d_ws, size_t ws_size,
                              hipStream_t stream) {
  const float* x = (const float*)d_in[0];     // [4096][3072]
  const float* wqkv = (const float*)d_in[1];  // [9216][3072]
  const float* wo = (const float*)d_in[2];    // [3072][3072]
  const float* bo = (const float*)d_in[3];    // [3072]
  float* out = (float*)d_out;                 // [4096][3072]
  char* ws = (char*)d_ws;

  const size_t E_X = (size_t)4096 * 3072;
  const size_t E_WQ = (size_t)9216 * 3072;
  const size_t E_WO = (size_t)3072 * 3072;

  // layout (bytes): X2[4E_X] | W2[4E_WQ] | Q2[4E_X] | KP[4E_X] | VP[4E_X]
  // | WO2[4E_WO].  After GEMM1, W2 region is dead -> AO2 reuses it.
  u16* X2 = (u16*)ws;
  char* W0 = ws + 4 * E_X;
  u16* W2 = (u16*)W0;
  u16* Q2 = (u16*)(W0 + 4 * E_WQ);
  u16* KP = Q2 + 2 * E_X;
  u16* VP = KP + 2 * E_X;
  u16* WO2 = VP + 2 * E_X;
  u16* AO2 = (u16*)W0;

  const size_t need = 4 * (4 * E_X + E_WQ + E_WO);  // 352.3 MB
  if (ws_size < need) return;

  split_fused<<<24576, 256, 0, stream>>>(x, X2, wqkv, W2, wo, WO2);
  gemm32<2><<<1536, 256, 0, stream>>>(X2, W2, 4096, 9216, Q2, KP, VP,
                                      nullptr, nullptr);
  attn_kernel<<<1024, 256, 0, stream>>>(Q2, KP, VP, AO2);
  gemm32<1><<<512, 256, 0, stream>>>(AO2, WO2, 4096, 3072, nullptr, nullptr,
                                     nullptr, out, bo);
}

// Round 22
// 1152.784 us; speedup vs baseline: 1.0773x; 1.0030x over previous
//
#include <hip/hip_runtime.h>
#include <math.h>

// fp32 attention layer via split-bf16 (hi/lo) 3-term MFMA emulation.
// Interleaved storage: [row][(col/32)*64 + col%32 + plane*32].
// r22: anti-phase stagger in gemm32 -- co-resident block pairs (bid>>8
// parity) are offset by ~2300 cyc (s_sleep) so the two blocks per CU
// alternate LDS-read and MFMA phases instead of colliding in-phase
// (measured: per-tile time = LDS+MFMA SUM, i.e. pipes serialize).
// Rest: r21 (fused splits, r16 GEMM structure + fused pack, r16 attn).

typedef unsigned int u32;
typedef unsigned short u16;
typedef __attribute__((ext_vector_type(8))) short bf16x8;
typedef __attribute__((ext_vector_type(4))) float f32x4;
typedef __attribute__((ext_vector_type(16))) float f32x16;

#define MFMA(a, b, c) __builtin_amdgcn_mfma_f32_16x16x32_bf16((a), (b), (c), 0, 0, 0)
#define MFMA32(a, b, c) __builtin_amdgcn_mfma_f32_32x32x16_bf16((a), (b), (c), 0, 0, 0)

#define GLDS16(g, l) __builtin_amdgcn_global_load_lds( \
    (const __attribute__((address_space(1))) u32*)(g), \
    (__attribute__((address_space(3))) u32*)(l), 16, 0, 0)

__device__ __forceinline__ u16 f2bf(float f) {
  u32 u = __builtin_bit_cast(u32, f);
  return (u16)((u + 0x7fffu + ((u >> 16) & 1u)) >> 16);  // RNE
}
__device__ __forceinline__ float bf2f(u16 h) {
  u32 u = ((u32)h) << 16;
  return __builtin_bit_cast(float, u);
}
__device__ __forceinline__ void split2(float f, u16& h, u16& l) {
  h = f2bf(f);
  l = f2bf(f - bf2f(h));
}
__device__ __forceinline__ bf16x8 ld16(const u16* p) {
  return *reinterpret_cast<const bf16x8*>(p);
}

// ---------------------------------------------------------------- split ----
// Fused: blocks [0,6144) x->X2, [6144,19968) wqkv->W2, [19968,24576) wo->WO2.
// fp32 [R][3072] -> interleaved hi/lo u16 [R][6144], 8 floats/thread.
__global__ void split_fused(const float* __restrict__ x, u16* __restrict__ X2,
                            const float* __restrict__ wq, u16* __restrict__ W2,
                            const float* __restrict__ wo, u16* __restrict__ WO2) {
  const float* src;
  u16* dst;
  int blk = blockIdx.x;
  if (blk < 6144) {
    src = x; dst = X2;
  } else if (blk < 19968) {
    src = wq; dst = W2; blk -= 6144;
  } else {
    src = wo; dst = WO2; blk -= 19968;
  }
  const long i = ((long)blk * 256 + threadIdx.x) * 8;
  const float4 v0 = *reinterpret_cast<const float4*>(src + i);
  const float4 v1 = *reinterpret_cast<const float4*>(src + i + 4);
  const u32 i32 = (u32)i;
  const u32 row = i32 / 3072u;
  const u32 col = i32 - row * 3072u;
  const long base = (long)row * 6144 + (col >> 5) * 64 + (col & 31);
  bf16x8 hv, lv;
  u16 h, l;
  split2(v0.x, h, l); hv[0] = (short)h; lv[0] = (short)l;
  split2(v0.y, h, l); hv[1] = (short)h; lv[1] = (short)l;
  split2(v0.z, h, l); hv[2] = (short)h; lv[2] = (short)l;
  split2(v0.w, h, l); hv[3] = (short)h; lv[3] = (short)l;
  split2(v1.x, h, l); hv[4] = (short)h; lv[4] = (short)l;
  split2(v1.y, h, l); hv[5] = (short)h; lv[5] = (short)l;
  split2(v1.z, h, l); hv[6] = (short)h; lv[6] = (short)l;
  split2(v1.w, h, l); hv[7] = (short)h; lv[7] = (short)l;
  *reinterpret_cast<bf16x8*>(dst + base) = hv;
  *reinterpret_cast<bf16x8*>(dst + base + 32) = lv;
}

// --------------------------------------- 128x192 3-term GEMM, 32x32x16 ----
// C = Ah*Bh^T + Ah*Bl^T + Al*Bh^T; A2[M][6144], B2[N][6144] interleaved.
// K=3072 -> NT=96 tiles of 32 (2 MFMA k-subs of 16). 4 waves (2M x 2N),
// wave tile 64x96, acc 6 x f32x16 = 96 VGPR. LDS 80 KiB -> 2 blocks/CU.
// Anti-phase stagger: odd (bid>>8) blocks sleep ~2300 cyc pre-prologue.
// MODE 1: fp32 C + bias (o_proj). MODE 2: QKV epilogue -- bn<16: compact
// Q2 [4096][6144]; bn 16..31: K packed records; bn>=32: V^T packed records
// (LDS-transpose via P[2][64][200], reusing staging LDS post-loop).
template <int MODE>
__global__ __launch_bounds__(256, 2) void gemm32(
    const u16* __restrict__ A2, const u16* __restrict__ B2,
    int M, int N, u16* __restrict__ C2, u16* __restrict__ Kp,
    u16* __restrict__ Vp, float* __restrict__ Cf, const float* __restrict__ bias) {
  constexpr int NT = 96;
  __shared__ u16 shm[2 * 128 * 64 + 2 * 192 * 64];  // 80 KiB
  u16* const uA = shm;                  // 2 x 128x64
  u16* const uB = shm + 2 * 128 * 64;   // 2 x 192x64
  const int tid = threadIdx.x;
  const int lane = tid & 63;
  const int w = tid >> 6;             // 0..3
  const int wm = w >> 1, wn = w & 1;  // 2M x 2N
  const int l31 = lane & 31;
  const int l5 = lane >> 5;

  const int mt = M >> 7;  // 128-row tiles
  const int nwg = gridDim.x;
  const int bid = blockIdx.x;

  // anti-phase stagger: co-resident pair = (bid, bid+256) under round-robin
  // dispatch; offset odd pair-members by ~half an in-phase tile.
  if ((bid >> 8) & 1) {
    __builtin_amdgcn_s_sleep(12);
    __builtin_amdgcn_s_sleep(12);
    __builtin_amdgcn_s_sleep(12);
  }

  const int wg = (bid & 7) * (nwg >> 3) + (bid >> 3);  // XCD swizzle (nwg%8==0)
  const int bm = wg % mt, bn = wg / mt;

  const int srow = lane >> 3;  // 0..7
  // stage rows = j*32 + w*8 + srow -> key(row) = (row&7)^((row>>3)&3) = srow^w
  const int sgc = ((lane & 7) ^ srow ^ w) * 8;

  auto stA = [&](int buf, int kt, int j) {
    const int r = j * 32 + w * 8 + srow;
    GLDS16(A2 + (long)(bm * 128 + r) * 6144 + kt * 64 + sgc,
           &uA[buf * 8192 + (j * 32 + w * 8) * 64]);
  };
  auto stB = [&](int buf, int kt, int j) {
    const int r = j * 32 + w * 8 + srow;
    GLDS16(B2 + (long)(bn * 192 + r) * 6144 + kt * 64 + sgc,
           &uB[buf * 12288 + (j * 32 + w * 8) * 64]);
  };

  f32x16 acc[2][3];
#pragma unroll
  for (int m = 0; m < 2; ++m)
#pragma unroll
    for (int n = 0; n < 3; ++n)
#pragma unroll
      for (int j = 0; j < 16; ++j) acc[m][n][j] = 0.f;

  // prologue
  stA(0, 0, 0); stA(0, 0, 1); stA(0, 0, 2); stA(0, 0, 3);
  stB(0, 0, 0); stB(0, 0, 1); stB(0, 0, 2);
  stB(0, 0, 3); stB(0, 0, 4); stB(0, 0, 5);
  __syncthreads();

  const int aRow0 = wm * 64 + l31;
  const int bRow0 = wn * 96 + l31;
  const int rk = (lane & 7) ^ ((lane >> 3) & 3);

#define CSLOT(KS, PL) ((((KS)*2 + l5 + (PL)*4) ^ rk) * 8)
#define RD_PH(KS)                                                          \
  _Pragma("unroll") for (int n = 0; n < 3; ++n) {                          \
    const int off = (bRow0 + n * 32) * 64;                                 \
    b[n][0] = ld16(&LB[off + CSLOT(KS, 0)]);                               \
    b[n][1] = ld16(&LB[off + CSLOT(KS, 1)]);                               \
  }                                                                        \
  _Pragma("unroll") for (int m = 0; m < 2; ++m) {                          \
    const int off = (aRow0 + m * 32) * 64;                                 \
    a[m][0] = ld16(&LA[off + CSLOT(KS, 0)]);                               \
    a[m][1] = ld16(&LA[off + CSLOT(KS, 1)]);                               \
  }
#define DO_MFMA3()                                                         \
  __builtin_amdgcn_s_setprio(1);                                           \
  _Pragma("unroll") for (int m = 0; m < 2; ++m)                            \
  _Pragma("unroll") for (int n = 0; n < 3; ++n) {                          \
    acc[m][n] = MFMA32(a[m][0], b[n][0], acc[m][n]);                       \
    acc[m][n] = MFMA32(a[m][0], b[n][1], acc[m][n]);                       \
    acc[m][n] = MFMA32(a[m][1], b[n][0], acc[m][n]);                       \
  }                                                                        \
  __builtin_amdgcn_s_setprio(0);
#define PH_SYNC()                                                          \
  __builtin_amdgcn_s_barrier();                                            \
  asm volatile("s_waitcnt lgkmcnt(0)" ::: "memory");                       \
  __builtin_amdgcn_sched_barrier(0);

  for (int t = 0; t < NT; ++t) {
    const int cur = t & 1;
    const int nxt = cur ^ 1;
    const u16* LA = &uA[cur * 8192];
    const u16* LB = &uB[cur * 12288];
    bf16x8 a[2][2], b[3][2];
    RD_PH(0);
    if (t + 1 < NT) {
      stA(nxt, t + 1, 0); stA(nxt, t + 1, 1);
      stA(nxt, t + 1, 2); stA(nxt, t + 1, 3);
      stB(nxt, t + 1, 0); stB(nxt, t + 1, 1); stB(nxt, t + 1, 2);
      stB(nxt, t + 1, 3); stB(nxt, t + 1, 4); stB(nxt, t + 1, 5);
    }
    PH_SYNC();
    DO_MFMA3();
    __builtin_amdgcn_s_barrier();
    RD_PH(1);
    PH_SYNC();
    DO_MFMA3();
    asm volatile("s_waitcnt vmcnt(0)" ::: "memory");
    __builtin_amdgcn_s_barrier();
  }
#undef CSLOT
#undef RD_PH
#undef DO_MFMA3
#undef PH_SYNC

  // epilogue. C/D: col=lane&31, row=(reg&3)+8*(reg>>2)+4*(lane>>5) (m101)
  if (MODE == 1 || (MODE == 2 && bn < 16)) {
#pragma unroll
    for (int mf = 0; mf < 2; ++mf)
#pragma unroll
      for (int nf = 0; nf < 3; ++nf) {
        const int col = bn * 192 + wn * 96 + nf * 32 + l31;
#pragma unroll
        for (int reg = 0; reg < 16; ++reg) {
          const int rif = (reg & 3) + 8 * (reg >> 2) + 4 * l5;
          const long row = (long)bm * 128 + wm * 64 + mf * 32 + rif;
          const float v = acc[mf][nf][reg];
          if (MODE == 1) {
            Cf[row * N + col] = v + bias[col];
          } else {  // compact Q2 [4096][6144]
            const long idx = row * 6144 + (col >> 5) * 64 + (col & 31);
            u16 h, l;
            split2(v, h, l);
            C2[idx] = h;
            C2[idx + 32] = l;
          }
        }
      }
  } else if (MODE == 2) {
    // K/V packed epilogue via LDS transpose. P[pl][64 s][200] (51.2 KB).
    const bool isV = (bn >= 32);
    const int hd0 = (bn - (isV ? 32 : 16)) * 2;  // first of 2 heads
    const int b = (bm * 128) >> 11;
    const int s_loc = (bm * 128) & 2047;
    u16* const P = shm;
    u16* const dst = isV ? Vp : Kp;
#pragma unroll
    for (int hf = 0; hf < 2; ++hf) {
      __syncthreads();
      if (wm == hf) {  // this wave owns rows hf*64 .. hf*64+63
#pragma unroll
        for (int mf = 0; mf < 2; ++mf)
#pragma unroll
          for (int nf = 0; nf < 3; ++nf)
#pragma unroll
            for (int reg = 0; reg < 16; ++reg) {
              const int rif = (reg & 3) + 8 * (reg >> 2) + 4 * l5;
              const int row_l = mf * 32 + rif;                // 0..63
              const int col_l = wn * 96 + nf * 32 + l31;      // 0..191
              u16 h, l;
              split2(acc[mf][nf][reg], h, l);
              P[row_l * 200 + col_l] = h;
              P[(64 + row_l) * 200 + col_l] = l;
            }
      }
      __syncthreads();
      const int lr = lane & 15, lg = lane >> 4;
      if (!isV) {
        // 48 records: ri = ((hh*3+c)*4+kbi)*2+pl; rec covers 16s x 32d.
#pragma unroll
        for (int i = 0; i < 12; ++i) {
          const int ri = w * 12 + i;
          const int pl = ri & 1;
          const int kbi = (ri >> 1) & 3;
          const int c = (ri >> 3) % 3;
          const int hh = ri / 24;
          const bf16x8 v =
              ld16(&P[(pl * 64 + kbi * 16 + lr) * 200 + hh * 96 + c * 32 + lg * 8]);
          const int hl = b * 32 + hd0 + hh;
          const int kbg = ((s_loc + hf * 64) >> 4) + kbi;
          const long rec3 = ((long)hl * 128 + kbg) * 3 + c;
          *reinterpret_cast<bf16x8*>(dst + (rec3 * 2 + pl) * 512 + lane * 8) = v;
        }
      } else {
        // 48 records: ri = ((hh*6+n)*2+kq)*2+pl; lane holds V^T[n*16+lr][..s..]
#pragma unroll
        for (int i = 0; i < 12; ++i) {
          const int ri = w * 12 + i;
          const int pl = ri & 1;
          const int kq = (ri >> 1) & 1;
          const int n = (ri >> 2) % 6;
          const int hh = ri / 24;
          bf16x8 v;
#pragma unroll
          for (int e = 0; e < 8; ++e)
            v[e] = (short)P[(pl * 64 + kq * 32 + lg * 8 + e) * 200 + hh * 96 + n * 16 + lr];
          const int hl = b * 32 + hd0 + hh;
          const int kqg = ((s_loc + hf * 64) >> 5) + kq;
          const long rec = (((long)hl * 6 + n) * 64 + kqg) * 2 + pl;
          *reinterpret_cast<bf16x8*>(dst + rec * 512 + lane * 8) = v;
        }
      }
    }
  }
}

// ------------------------------------------------------------- attention ---
// r16 version (best-measured): 32 q-rows/wave (2 frags), block = 128
// q-rows; K/V LDS-staged (shared), launch_bounds(256,2). Q from compact
// Q2 [4096][6144]. Max-free softmax.
__global__ __launch_bounds__(256, 2) void attn_kernel(
    const u16* __restrict__ Q2,
    const u16* __restrict__ Kp, const u16* __restrict__ Vp,
    u16* __restrict__ AO2) {
  __shared__ u16 kv[2][24 * 512];   // 48 KB
  __shared__ u16 pb[4][2][2][512];  // 16 KB: [wave][frag][plane]
  const int lane = threadIdx.x & 63;
  const int wv = threadIdx.x >> 6;
  const int lr = lane & 15, lg = lane >> 4;

  const int nwg = gridDim.x;
  const int bid = blockIdx.x;
  const int wg = (bid & 7) * (nwg >> 3) + (bid >> 3);  // XCD swizzle
  const int hl = wg >> 4;    // b*32 + head
  const int qblk = wg & 15;  // 16 q-blocks of 128 rows
  const int b = hl >> 5;
  const int q0 = qblk * 128 + wv * 32;

  bf16x8 qh[2][3], ql[2][3];
#pragma unroll
  for (int f = 0; f < 2; ++f) {
    const long qofs =
        ((long)(b * 2048 + q0 + f * 16 + lr)) * 6144 + ((hl & 31) * 3) * 64 + lg * 8;
#pragma unroll
    for (int c = 0; c < 3; ++c) {
      qh[f][c] = ld16(Q2 + qofs + c * 64);
      ql[f][c] = ld16(Q2 + qofs + c * 64 + 32);
    }
  }

  f32x4 o_acc[2][6];
#pragma unroll
  for (int f = 0; f < 2; ++f)
#pragma unroll
    for (int n = 0; n < 6; ++n)
#pragma unroll
      for (int j = 0; j < 4; ++j) o_acc[f][n][j] = 0.f;
  float lsum[2][4] = {{0.f, 0.f, 0.f, 0.f}, {0.f, 0.f, 0.f, 0.f}};

  const float scale = 0.10206207261596577f;  // 96^-0.5

  auto stage = [&](int nb, int it) {
    const long kbase = ((long)hl * 768 + (long)it * 12) * 512;
    const long vbase = ((long)hl * 768 + (long)it * 2) * 512;
#pragma unroll
    for (int j = 0; j < 6; ++j) {
      const int r = wv * 6 + j;
      const u16* src;
      if (r < 12) {
        const int tt = r / 6, rc = r % 6;
        src = Kp + kbase + ((long)(tt * 6 + rc)) * 512 + lane * 8;
      } else {
        const int r2 = r - 12;
        src = Vp + vbase + ((long)((r2 >> 1) * 128 + (r2 & 1))) * 512 + lane * 8;
      }
      GLDS16(src, &kv[nb][r * 512]);
    }
  };

  stage(0, 0);
  __syncthreads();

  for (int it = 0; it < 64; ++it) {
    const int nb = it & 1;
    if (it < 63) stage(nb ^ 1, it + 1);
    const u16* L = kv[nb];

    bf16x8 kh0[3], kl0[3], kh1[3], kl1[3];
#pragma unroll
    for (int c = 0; c < 3; ++c) {
      kh0[c] = ld16(L + (c * 2 + 0) * 512 + lane * 8);
      kl0[c] = ld16(L + (c * 2 + 1) * 512 + lane * 8);
      kh1[c] = ld16(L + (6 + c * 2 + 0) * 512 + lane * 8);
      kl1[c] = ld16(L + (6 + c * 2 + 1) * 512 + lane * 8);
    }

    bf16x8 pah[2], pal[2];
#pragma unroll
    for (int f = 0; f < 2; ++f) {
      f32x4 s0, s1;
#pragma unroll
      for (int j = 0; j < 4; ++j) { s0[j] = 0.f; s1[j] = 0.f; }
#pragma unroll
      for (int c = 0; c < 3; ++c) {
        s0 = MFMA(qh[f][c], kh0[c], s0);
        s1 = MFMA(qh[f][c], kh1[c], s1);
        s0 = MFMA(qh[f][c], kl0[c], s0);
        s1 = MFMA(qh[f][c], kl1[c], s1);
        s0 = MFMA(ql[f][c], kh0[c], s0);
        s1 = MFMA(ql[f][c], kh1[c], s1);
      }
      u16* pbh = pb[wv][f][0];
      u16* pbl = pb[wv][f][1];
#pragma unroll
      for (int j = 0; j < 4; ++j) {
        const float p0 = __expf(fmaf(s0[j], scale, -12.f));
        const float p1 = __expf(fmaf(s1[j], scale, -12.f));
        lsum[f][j] += p0 + p1;
        const int r = lg * 4 + j;
        const int key = j ^ lg;
        u16 h, l;
        split2(p0, h, l);
        const int a0 = r * 32 + ((((lr >> 3) ^ key) & 3) << 3) + (lr & 7);
        pbh[a0] = h;
        pbl[a0] = l;
        split2(p1, h, l);
        const int a1 = r * 32 + ((((2 + (lr >> 3)) ^ key) & 3) << 3) + (lr & 7);
        pbh[a1] = h;
        pbl[a1] = l;
      }
      const int rkey = (lr & 3) ^ (lr >> 2);
      const int ra = lr * 32 + (((lg ^ rkey) & 3) << 3);
      pah[f] = ld16(&pbh[ra]);
      pal[f] = ld16(&pbl[ra]);
    }

#pragma unroll
    for (int n = 0; n < 6; ++n) {
      const bf16x8 vh = ld16(L + (12 + n * 2 + 0) * 512 + lane * 8);
      const bf16x8 vl = ld16(L + (12 + n * 2 + 1) * 512 + lane * 8);
#pragma unroll
      for (int f = 0; f < 2; ++f) {
        o_acc[f][n] = MFMA(pah[f], vh, o_acc[f][n]);
        o_acc[f][n] = MFMA(pah[f], vl, o_acc[f][n]);
        o_acc[f][n] = MFMA(pal[f], vh, o_acc[f][n]);
      }
    }
    __syncthreads();
  }

#pragma unroll
  for (int f = 0; f < 2; ++f) {
    float inv[4];
#pragma unroll
    for (int j = 0; j < 4; ++j) {
      float rs = lsum[f][j];
#pragma unroll
      for (int mk = 1; mk < 16; mk <<= 1) rs += __shfl_xor(rs, mk);
      inv[j] = 1.f / rs;
    }
#pragma unroll
    for (int n = 0; n < 6; ++n)
#pragma unroll
      for (int j = 0; j < 4; ++j) {
        const long row = (long)(b * 2048 + q0 + f * 16 + lg * 4 + j);
        const long idx =
            row * 6144 + ((hl & 31) * 3 + (n >> 1)) * 64 + (n & 1) * 16 + lr;
        u16 h, l;
        split2(o_acc[f][n][j] * inv[j], h, l);
        AO2[idx] = h;
        AO2[idx + 32] = l;
      }
  }
}

// ---------------------------------------------------------------- launch ---
extern "C" void kernel_launch(void* const* d_in, const int* in_sizes, int n_in,
                              void* d_out, int out_size, void* d_ws, size_t ws_size,
                              hipStream_t stream) {
  const float* x = (const float*)d_in[0];     // [4096][3072]
  const float* wqkv = (const float*)d_in[1];  // [9216][3072]
  const float* wo = (const float*)d_in[2];    // [3072][3072]
  const float* bo = (const float*)d_in[3];    // [3072]
  float* out = (float*)d_out;                 // [4096][3072]
  char* ws = (char*)d_ws;

  const size_t E_X = (size_t)4096 * 3072;
  const size_t E_WQ = (size_t)9216 * 3072;
  const size_t E_WO = (size_t)3072 * 3072;

  // layout (bytes): X2[4E_X] | W2[4E_WQ] | Q2[4E_X] | KP[4E_X] | VP[4E_X]
  // | WO2[4E_WO].  After GEMM1, W2 region is dead -> AO2 reuses it.
  u16* X2 = (u16*)ws;
  char* W0 = ws + 4 * E_X;
  u16* W2 = (u16*)W0;
  u16* Q2 = (u16*)(W0 + 4 * E_WQ);
  u16* KP = Q2 + 2 * E_X;
  u16* VP = KP + 2 * E_X;
  u16* WO2 = VP + 2 * E_X;
  u16* AO2 = (u16*)W0;

  const size_t need = 4 * (4 * E_X + E_WQ + E_WO);  // 352.3 MB
  if (ws_size < need) return;

  split_fused<<<24576, 256, 0, stream>>>(x, X2, wqkv, W2, wo, WO2);
  gemm32<2><<<1536, 256, 0, stream>>>(X2, W2, 4096, 9216, Q2, KP, VP,
                                      nullptr, nullptr);
  attn_kernel<<<1024, 256, 0, stream>>>(Q2, KP, VP, AO2);
  gemm32<1><<<512, 256, 0, stream>>>(AO2, WO2, 4096, 3072, nullptr, nullptr,
                                     nullptr, out, bo);
}

// Round 23
// 1134.306 us; speedup vs baseline: 1.0948x; 1.0163x over previous
//
#include <hip/hip_runtime.h>
#include <math.h>

// fp32 attention layer via split-bf16 (hi/lo) 3-term MFMA emulation.
// Interleaved storage: [row][(col/32)*64 + col%32 + plane*32].
// r23: stagger removed (r22: neutral, first-round outlier). T5 setprio
// added around attn's QK^T and PV MFMA clusters (m191: +4-7% attn).
// Rest: r21 (fused splits, r16 GEMM + fused QKV pack, r16 attn).

typedef unsigned int u32;
typedef unsigned short u16;
typedef __attribute__((ext_vector_type(8))) short bf16x8;
typedef __attribute__((ext_vector_type(4))) float f32x4;
typedef __attribute__((ext_vector_type(16))) float f32x16;

#define MFMA(a, b, c) __builtin_amdgcn_mfma_f32_16x16x32_bf16((a), (b), (c), 0, 0, 0)
#define MFMA32(a, b, c) __builtin_amdgcn_mfma_f32_32x32x16_bf16((a), (b), (c), 0, 0, 0)

#define GLDS16(g, l) __builtin_amdgcn_global_load_lds( \
    (const __attribute__((address_space(1))) u32*)(g), \
    (__attribute__((address_space(3))) u32*)(l), 16, 0, 0)

__device__ __forceinline__ u16 f2bf(float f) {
  u32 u = __builtin_bit_cast(u32, f);
  return (u16)((u + 0x7fffu + ((u >> 16) & 1u)) >> 16);  // RNE
}
__device__ __forceinline__ float bf2f(u16 h) {
  u32 u = ((u32)h) << 16;
  return __builtin_bit_cast(float, u);
}
__device__ __forceinline__ void split2(float f, u16& h, u16& l) {
  h = f2bf(f);
  l = f2bf(f - bf2f(h));
}
__device__ __forceinline__ bf16x8 ld16(const u16* p) {
  return *reinterpret_cast<const bf16x8*>(p);
}

// ---------------------------------------------------------------- split ----
// Fused: blocks [0,6144) x->X2, [6144,19968) wqkv->W2, [19968,24576) wo->WO2.
// fp32 [R][3072] -> interleaved hi/lo u16 [R][6144], 8 floats/thread.
__global__ void split_fused(const float* __restrict__ x, u16* __restrict__ X2,
                            const float* __restrict__ wq, u16* __restrict__ W2,
                            const float* __restrict__ wo, u16* __restrict__ WO2) {
  const float* src;
  u16* dst;
  int blk = blockIdx.x;
  if (blk < 6144) {
    src = x; dst = X2;
  } else if (blk < 19968) {
    src = wq; dst = W2; blk -= 6144;
  } else {
    src = wo; dst = WO2; blk -= 19968;
  }
  const long i = ((long)blk * 256 + threadIdx.x) * 8;
  const float4 v0 = *reinterpret_cast<const float4*>(src + i);
  const float4 v1 = *reinterpret_cast<const float4*>(src + i + 4);
  const u32 i32 = (u32)i;
  const u32 row = i32 / 3072u;
  const u32 col = i32 - row * 3072u;
  const long base = (long)row * 6144 + (col >> 5) * 64 + (col & 31);
  bf16x8 hv, lv;
  u16 h, l;
  split2(v0.x, h, l); hv[0] = (short)h; lv[0] = (short)l;
  split2(v0.y, h, l); hv[1] = (short)h; lv[1] = (short)l;
  split2(v0.z, h, l); hv[2] = (short)h; lv[2] = (short)l;
  split2(v0.w, h, l); hv[3] = (short)h; lv[3] = (short)l;
  split2(v1.x, h, l); hv[4] = (short)h; lv[4] = (short)l;
  split2(v1.y, h, l); hv[5] = (short)h; lv[5] = (short)l;
  split2(v1.z, h, l); hv[6] = (short)h; lv[6] = (short)l;
  split2(v1.w, h, l); hv[7] = (short)h; lv[7] = (short)l;
  *reinterpret_cast<bf16x8*>(dst + base) = hv;
  *reinterpret_cast<bf16x8*>(dst + base + 32) = lv;
}

// --------------------------------------- 128x192 3-term GEMM, 32x32x16 ----
// C = Ah*Bh^T + Ah*Bl^T + Al*Bh^T; A2[M][6144], B2[N][6144] interleaved.
// K=3072 -> NT=96 tiles of 32 (2 MFMA k-subs of 16). 4 waves (2M x 2N),
// wave tile 64x96, acc 6 x f32x16 = 96 VGPR. LDS 80 KiB -> 2 blocks/CU.
// MODE 1: fp32 C + bias (o_proj). MODE 2: QKV epilogue -- bn<16: compact
// Q2 [4096][6144]; bn 16..31: K packed records; bn>=32: V^T packed records
// (LDS-transpose via P[2][64][200], reusing staging LDS post-loop).
template <int MODE>
__global__ __launch_bounds__(256, 2) void gemm32(
    const u16* __restrict__ A2, const u16* __restrict__ B2,
    int M, int N, u16* __restrict__ C2, u16* __restrict__ Kp,
    u16* __restrict__ Vp, float* __restrict__ Cf, const float* __restrict__ bias) {
  constexpr int NT = 96;
  __shared__ u16 shm[2 * 128 * 64 + 2 * 192 * 64];  // 80 KiB
  u16* const uA = shm;                  // 2 x 128x64
  u16* const uB = shm + 2 * 128 * 64;   // 2 x 192x64
  const int tid = threadIdx.x;
  const int lane = tid & 63;
  const int w = tid >> 6;             // 0..3
  const int wm = w >> 1, wn = w & 1;  // 2M x 2N
  const int l31 = lane & 31;
  const int l5 = lane >> 5;

  const int mt = M >> 7;  // 128-row tiles
  const int nwg = gridDim.x;
  const int bid = blockIdx.x;
  const int wg = (bid & 7) * (nwg >> 3) + (bid >> 3);  // XCD swizzle (nwg%8==0)
  const int bm = wg % mt, bn = wg / mt;

  const int srow = lane >> 3;  // 0..7
  // stage rows = j*32 + w*8 + srow -> key(row) = (row&7)^((row>>3)&3) = srow^w
  const int sgc = ((lane & 7) ^ srow ^ w) * 8;

  auto stA = [&](int buf, int kt, int j) {
    const int r = j * 32 + w * 8 + srow;
    GLDS16(A2 + (long)(bm * 128 + r) * 6144 + kt * 64 + sgc,
           &uA[buf * 8192 + (j * 32 + w * 8) * 64]);
  };
  auto stB = [&](int buf, int kt, int j) {
    const int r = j * 32 + w * 8 + srow;
    GLDS16(B2 + (long)(bn * 192 + r) * 6144 + kt * 64 + sgc,
           &uB[buf * 12288 + (j * 32 + w * 8) * 64]);
  };

  f32x16 acc[2][3];
#pragma unroll
  for (int m = 0; m < 2; ++m)
#pragma unroll
    for (int n = 0; n < 3; ++n)
#pragma unroll
      for (int j = 0; j < 16; ++j) acc[m][n][j] = 0.f;

  // prologue
  stA(0, 0, 0); stA(0, 0, 1); stA(0, 0, 2); stA(0, 0, 3);
  stB(0, 0, 0); stB(0, 0, 1); stB(0, 0, 2);
  stB(0, 0, 3); stB(0, 0, 4); stB(0, 0, 5);
  __syncthreads();

  const int aRow0 = wm * 64 + l31;
  const int bRow0 = wn * 96 + l31;
  const int rk = (lane & 7) ^ ((lane >> 3) & 3);

#define CSLOT(KS, PL) ((((KS)*2 + l5 + (PL)*4) ^ rk) * 8)
#define RD_PH(KS)                                                          \
  _Pragma("unroll") for (int n = 0; n < 3; ++n) {                          \
    const int off = (bRow0 + n * 32) * 64;                                 \
    b[n][0] = ld16(&LB[off + CSLOT(KS, 0)]);                               \
    b[n][1] = ld16(&LB[off + CSLOT(KS, 1)]);                               \
  }                                                                        \
  _Pragma("unroll") for (int m = 0; m < 2; ++m) {                          \
    const int off = (aRow0 + m * 32) * 64;                                 \
    a[m][0] = ld16(&LA[off + CSLOT(KS, 0)]);                               \
    a[m][1] = ld16(&LA[off + CSLOT(KS, 1)]);                               \
  }
#define DO_MFMA3()                                                         \
  __builtin_amdgcn_s_setprio(1);                                           \
  _Pragma("unroll") for (int m = 0; m < 2; ++m)                            \
  _Pragma("unroll") for (int n = 0; n < 3; ++n) {                          \
    acc[m][n] = MFMA32(a[m][0], b[n][0], acc[m][n]);                       \
    acc[m][n] = MFMA32(a[m][0], b[n][1], acc[m][n]);                       \
    acc[m][n] = MFMA32(a[m][1], b[n][0], acc[m][n]);                       \
  }                                                                        \
  __builtin_amdgcn_s_setprio(0);
#define PH_SYNC()                                                          \
  __builtin_amdgcn_s_barrier();                                            \
  asm volatile("s_waitcnt lgkmcnt(0)" ::: "memory");                       \
  __builtin_amdgcn_sched_barrier(0);

  for (int t = 0; t < NT; ++t) {
    const int cur = t & 1;
    const int nxt = cur ^ 1;
    const u16* LA = &uA[cur * 8192];
    const u16* LB = &uB[cur * 12288];
    bf16x8 a[2][2], b[3][2];
    RD_PH(0);
    if (t + 1 < NT) {
      stA(nxt, t + 1, 0); stA(nxt, t + 1, 1);
      stA(nxt, t + 1, 2); stA(nxt, t + 1, 3);
      stB(nxt, t + 1, 0); stB(nxt, t + 1, 1); stB(nxt, t + 1, 2);
      stB(nxt, t + 1, 3); stB(nxt, t + 1, 4); stB(nxt, t + 1, 5);
    }
    PH_SYNC();
    DO_MFMA3();
    __builtin_amdgcn_s_barrier();
    RD_PH(1);
    PH_SYNC();
    DO_MFMA3();
    asm volatile("s_waitcnt vmcnt(0)" ::: "memory");
    __builtin_amdgcn_s_barrier();
  }
#undef CSLOT
#undef RD_PH
#undef DO_MFMA3
#undef PH_SYNC

  // epilogue. C/D: col=lane&31, row=(reg&3)+8*(reg>>2)+4*(lane>>5) (m101)
  if (MODE == 1 || (MODE == 2 && bn < 16)) {
#pragma unroll
    for (int mf = 0; mf < 2; ++mf)
#pragma unroll
      for (int nf = 0; nf < 3; ++nf) {
        const int col = bn * 192 + wn * 96 + nf * 32 + l31;
#pragma unroll
        for (int reg = 0; reg < 16; ++reg) {
          const int rif = (reg & 3) + 8 * (reg >> 2) + 4 * l5;
          const long row = (long)bm * 128 + wm * 64 + mf * 32 + rif;
          const float v = acc[mf][nf][reg];
          if (MODE == 1) {
            Cf[row * N + col] = v + bias[col];
          } else {  // compact Q2 [4096][6144]
            const long idx = row * 6144 + (col >> 5) * 64 + (col & 31);
            u16 h, l;
            split2(v, h, l);
            C2[idx] = h;
            C2[idx + 32] = l;
          }
        }
      }
  } else if (MODE == 2) {
    // K/V packed epilogue via LDS transpose. P[pl][64 s][200] (51.2 KB).
    const bool isV = (bn >= 32);
    const int hd0 = (bn - (isV ? 32 : 16)) * 2;  // first of 2 heads
    const int b = (bm * 128) >> 11;
    const int s_loc = (bm * 128) & 2047;
    u16* const P = shm;
    u16* const dst = isV ? Vp : Kp;
#pragma unroll
    for (int hf = 0; hf < 2; ++hf) {
      __syncthreads();
      if (wm == hf) {  // this wave owns rows hf*64 .. hf*64+63
#pragma unroll
        for (int mf = 0; mf < 2; ++mf)
#pragma unroll
          for (int nf = 0; nf < 3; ++nf)
#pragma unroll
            for (int reg = 0; reg < 16; ++reg) {
              const int rif = (reg & 3) + 8 * (reg >> 2) + 4 * l5;
              const int row_l = mf * 32 + rif;                // 0..63
              const int col_l = wn * 96 + nf * 32 + l31;      // 0..191
              u16 h, l;
              split2(acc[mf][nf][reg], h, l);
              P[row_l * 200 + col_l] = h;
              P[(64 + row_l) * 200 + col_l] = l;
            }
      }
      __syncthreads();
      const int lr = lane & 15, lg = lane >> 4;
      if (!isV) {
        // 48 records: ri = ((hh*3+c)*4+kbi)*2+pl; rec covers 16s x 32d.
#pragma unroll
        for (int i = 0; i < 12; ++i) {
          const int ri = w * 12 + i;
          const int pl = ri & 1;
          const int kbi = (ri >> 1) & 3;
          const int c = (ri >> 3) % 3;
          const int hh = ri / 24;
          const bf16x8 v =
              ld16(&P[(pl * 64 + kbi * 16 + lr) * 200 + hh * 96 + c * 32 + lg * 8]);
          const int hl = b * 32 + hd0 + hh;
          const int kbg = ((s_loc + hf * 64) >> 4) + kbi;
          const long rec3 = ((long)hl * 128 + kbg) * 3 + c;
          *reinterpret_cast<bf16x8*>(dst + (rec3 * 2 + pl) * 512 + lane * 8) = v;
        }
      } else {
        // 48 records: ri = ((hh*6+n)*2+kq)*2+pl; lane holds V^T[n*16+lr][..s..]
#pragma unroll
        for (int i = 0; i < 12; ++i) {
          const int ri = w * 12 + i;
          const int pl = ri & 1;
          const int kq = (ri >> 1) & 1;
          const int n = (ri >> 2) % 6;
          const int hh = ri / 24;
          bf16x8 v;
#pragma unroll
          for (int e = 0; e < 8; ++e)
            v[e] = (short)P[(pl * 64 + kq * 32 + lg * 8 + e) * 200 + hh * 96 + n * 16 + lr];
          const int hl = b * 32 + hd0 + hh;
          const int kqg = ((s_loc + hf * 64) >> 5) + kq;
          const long rec = (((long)hl * 6 + n) * 64 + kqg) * 2 + pl;
          *reinterpret_cast<bf16x8*>(dst + rec * 512 + lane * 8) = v;
        }
      }
    }
  }
}

// ------------------------------------------------------------- attention ---
// r16 structure + T5: setprio(1) around QK^T and PV MFMA clusters.
// 32 q-rows/wave (2 frags), block = 128 q-rows; K/V LDS-staged,
// launch_bounds(256,2). Q from compact Q2 [4096][6144]. Max-free softmax.
__global__ __launch_bounds__(256, 2) void attn_kernel(
    const u16* __restrict__ Q2,
    const u16* __restrict__ Kp, const u16* __restrict__ Vp,
    u16* __restrict__ AO2) {
  __shared__ u16 kv[2][24 * 512];   // 48 KB
  __shared__ u16 pb[4][2][2][512];  // 16 KB: [wave][frag][plane]
  const int lane = threadIdx.x & 63;
  const int wv = threadIdx.x >> 6;
  const int lr = lane & 15, lg = lane >> 4;

  const int nwg = gridDim.x;
  const int bid = blockIdx.x;
  const int wg = (bid & 7) * (nwg >> 3) + (bid >> 3);  // XCD swizzle
  const int hl = wg >> 4;    // b*32 + head
  const int qblk = wg & 15;  // 16 q-blocks of 128 rows
  const int b = hl >> 5;
  const int q0 = qblk * 128 + wv * 32;

  bf16x8 qh[2][3], ql[2][3];
#pragma unroll
  for (int f = 0; f < 2; ++f) {
    const long qofs =
        ((long)(b * 2048 + q0 + f * 16 + lr)) * 6144 + ((hl & 31) * 3) * 64 + lg * 8;
#pragma unroll
    for (int c = 0; c < 3; ++c) {
      qh[f][c] = ld16(Q2 + qofs + c * 64);
      ql[f][c] = ld16(Q2 + qofs + c * 64 + 32);
    }
  }

  f32x4 o_acc[2][6];
#pragma unroll
  for (int f = 0; f < 2; ++f)
#pragma unroll
    for (int n = 0; n < 6; ++n)
#pragma unroll
      for (int j = 0; j < 4; ++j) o_acc[f][n][j] = 0.f;
  float lsum[2][4] = {{0.f, 0.f, 0.f, 0.f}, {0.f, 0.f, 0.f, 0.f}};

  const float scale = 0.10206207261596577f;  // 96^-0.5

  auto stage = [&](int nb, int it) {
    const long kbase = ((long)hl * 768 + (long)it * 12) * 512;
    const long vbase = ((long)hl * 768 + (long)it * 2) * 512;
#pragma unroll
    for (int j = 0; j < 6; ++j) {
      const int r = wv * 6 + j;
      const u16* src;
      if (r < 12) {
        const int tt = r / 6, rc = r % 6;
        src = Kp + kbase + ((long)(tt * 6 + rc)) * 512 + lane * 8;
      } else {
        const int r2 = r - 12;
        src = Vp + vbase + ((long)((r2 >> 1) * 128 + (r2 & 1))) * 512 + lane * 8;
      }
      GLDS16(src, &kv[nb][r * 512]);
    }
  };

  stage(0, 0);
  __syncthreads();

  for (int it = 0; it < 64; ++it) {
    const int nb = it & 1;
    if (it < 63) stage(nb ^ 1, it + 1);
    const u16* L = kv[nb];

    bf16x8 kh0[3], kl0[3], kh1[3], kl1[3];
#pragma unroll
    for (int c = 0; c < 3; ++c) {
      kh0[c] = ld16(L + (c * 2 + 0) * 512 + lane * 8);
      kl0[c] = ld16(L + (c * 2 + 1) * 512 + lane * 8);
      kh1[c] = ld16(L + (6 + c * 2 + 0) * 512 + lane * 8);
      kl1[c] = ld16(L + (6 + c * 2 + 1) * 512 + lane * 8);
    }

    bf16x8 pah[2], pal[2];
#pragma unroll
    for (int f = 0; f < 2; ++f) {
      f32x4 s0, s1;
#pragma unroll
      for (int j = 0; j < 4; ++j) { s0[j] = 0.f; s1[j] = 0.f; }
      __builtin_amdgcn_s_setprio(1);  // T5: QK^T MFMA cluster
#pragma unroll
      for (int c = 0; c < 3; ++c) {
        s0 = MFMA(qh[f][c], kh0[c], s0);
        s1 = MFMA(qh[f][c], kh1[c], s1);
        s0 = MFMA(qh[f][c], kl0[c], s0);
        s1 = MFMA(qh[f][c], kl1[c], s1);
        s0 = MFMA(ql[f][c], kh0[c], s0);
        s1 = MFMA(ql[f][c], kh1[c], s1);
      }
      __builtin_amdgcn_s_setprio(0);
      u16* pbh = pb[wv][f][0];
      u16* pbl = pb[wv][f][1];
#pragma unroll
      for (int j = 0; j < 4; ++j) {
        const float p0 = __expf(fmaf(s0[j], scale, -12.f));
        const float p1 = __expf(fmaf(s1[j], scale, -12.f));
        lsum[f][j] += p0 + p1;
        const int r = lg * 4 + j;
        const int key = j ^ lg;
        u16 h, l;
        split2(p0, h, l);
        const int a0 = r * 32 + ((((lr >> 3) ^ key) & 3) << 3) + (lr & 7);
        pbh[a0] = h;
        pbl[a0] = l;
        split2(p1, h, l);
        const int a1 = r * 32 + ((((2 + (lr >> 3)) ^ key) & 3) << 3) + (lr & 7);
        pbh[a1] = h;
        pbl[a1] = l;
      }
      const int rkey = (lr & 3) ^ (lr >> 2);
      const int ra = lr * 32 + (((lg ^ rkey) & 3) << 3);
      pah[f] = ld16(&pbh[ra]);
      pal[f] = ld16(&pbl[ra]);
    }

    __builtin_amdgcn_s_setprio(1);  // T5: PV MFMA cluster
#pragma unroll
    for (int n = 0; n < 6; ++n) {
      const bf16x8 vh = ld16(L + (12 + n * 2 + 0) * 512 + lane * 8);
      const bf16x8 vl = ld16(L + (12 + n * 2 + 1) * 512 + lane * 8);
#pragma unroll
      for (int f = 0; f < 2; ++f) {
        o_acc[f][n] = MFMA(pah[f], vh, o_acc[f][n]);
        o_acc[f][n] = MFMA(pah[f], vl, o_acc[f][n]);
        o_acc[f][n] = MFMA(pal[f], vh, o_acc[f][n]);
      }
    }
    __builtin_amdgcn_s_setprio(0);
    __syncthreads();
  }

#pragma unroll
  for (int f = 0; f < 2; ++f) {
    float inv[4];
#pragma unroll
    for (int j = 0; j < 4; ++j) {
      float rs = lsum[f][j];
#pragma unroll
      for (int mk = 1; mk < 16; mk <<= 1) rs += __shfl_xor(rs, mk);
      inv[j] = 1.f / rs;
    }
#pragma unroll
    for (int n = 0; n < 6; ++n)
#pragma unroll
      for (int j = 0; j < 4; ++j) {
        const long row = (long)(b * 2048 + q0 + f * 16 + lg * 4 + j);
        const long idx =
            row * 6144 + ((hl & 31) * 3 + (n >> 1)) * 64 + (n & 1) * 16 + lr;
        u16 h, l;
        split2(o_acc[f][n][j] * inv[j], h, l);
        AO2[idx] = h;
        AO2[idx + 32] = l;
      }
  }
}

// ---------------------------------------------------------------- launch ---
extern "C" void kernel_launch(void* const* d_in, const int* in_sizes, int n_in,
                              void* d_out, int out_size, void* d_ws, size_t ws_size,
                              hipStream_t stream) {
  const float* x = (const float*)d_in[0];     // [4096][3072]
  const float* wqkv = (const float*)d_in[1];  // [9216][3072]
  const float* wo = (const float*)d_in[2];    // [3072][3072]
  const float* bo = (const float*)d_in[3];    // [3072]
  float* out = (float*)d_out;                 // [4096][3072]
  char* ws = (char*)d_ws;

  const size_t E_X = (size_t)4096 * 3072;
  const size_t E_WQ = (size_t)9216 * 3072;
  const size_t E_WO = (size_t)3072 * 3072;

  // layout (bytes): X2[4E_X] | W2[4E_WQ] | Q2[4E_X] | KP[4E_X] | VP[4E_X]
  // | WO2[4E_WO].  After GEMM1, W2 region is dead -> AO2 reuses it.
  u16* X2 = (u16*)ws;
  char* W0 = ws + 4 * E_X;
  u16* W2 = (u16*)W0;
  u16* Q2 = (u16*)(W0 + 4 * E_WQ);
  u16* KP = Q2 + 2 * E_X;
  u16* VP = KP + 2 * E_X;
  u16* WO2 = VP + 2 * E_X;
  u16* AO2 = (u16*)W0;

  const size_t need = 4 * (4 * E_X + E_WQ + E_WO);  // 352.3 MB
  if (ws_size < need) return;

  split_fused<<<24576, 256, 0, stream>>>(x, X2, wqkv, W2, wo, WO2);
  gemm32<2><<<1536, 256, 0, stream>>>(X2, W2, 4096, 9216, Q2, KP, VP,
                                      nullptr, nullptr);
  attn_kernel<<<1024, 256, 0, stream>>>(Q2, KP, VP, AO2);
  gemm32<1><<<512, 256, 0, stream>>>(AO2, WO2, 4096, 3072, nullptr, nullptr,
                                     nullptr, out, bo);
}